// Round 1
// baseline (179.135 us; speedup 1.0000x reference)
//
#include <hip/hip_runtime.h>
#include <math.h>

#define KSZ 7
#define KK 49
#define P 3
#define C 64
#define H 128
#define W 128
#define NB 4
#define EPS 1e-7f

// tile: 64 wide x 4 tall pixels per block (256 threads)
#define TW 64
#define TH 4
#define HALO_W (TW + 2 * P)   // 70
#define HALO_H (TH + 2 * P)   // 10
#define LDW 72                // padded LDS stride (lane-consecutive, conflict-free)
#define CG 8                  // channels staged per LDS pass

__global__ __launch_bounds__(256) void norms_kernel(const float* __restrict__ x,
                                                    float* __restrict__ nrm) {
    int idx = blockIdx.x * 256 + threadIdx.x;   // b*16384 + h*128 + w
    const float* px = x + ((size_t)(idx >> 14)) * (C * H * W) + (idx & 16383);
    float s = 0.f;
#pragma unroll
    for (int c = 0; c < C; ++c) {
        float v = px[c * H * W];
        s += v * v;
    }
    nrm[idx] = sqrtf(s);
}

__global__ __launch_bounds__(256) void sim_kernel(const float* __restrict__ x,
                                                  const float* __restrict__ nrm,
                                                  float* __restrict__ out) {
    __shared__ float sx[CG][HALO_H][LDW];
    __shared__ float sn[HALO_H][LDW];

    const int tx = threadIdx.x;          // 0..63
    const int ty = threadIdx.y;          // 0..3
    const int tid = ty * TW + tx;
    const int w0 = blockIdx.x * TW;
    const int h0 = blockIdx.y * TH;
    const int b  = blockIdx.z;

    // stage norm halo tile (once)
    for (int i = tid; i < HALO_H * HALO_W; i += 256) {
        int r = i / HALO_W, cc = i % HALO_W;
        int gh = h0 - P + r, gw = w0 - P + cc;
        float v = 0.f;
        if (gh >= 0 && gh < H && gw >= 0 && gw < W)
            v = nrm[(b << 14) + (gh << 7) + gw];
        sn[r][cc] = v;
    }

    float acc[KK];
#pragma unroll
    for (int k = 0; k < KK; ++k) acc[k] = 0.f;

    for (int cg = 0; cg < C; cg += CG) {
        __syncthreads();
        // stage CG channels of the halo tile
        for (int i = tid; i < CG * HALO_H * HALO_W; i += 256) {
            int c   = i / (HALO_H * HALO_W);
            int rem = i - c * (HALO_H * HALO_W);
            int r = rem / HALO_W, cc = rem - r * HALO_W;
            int gh = h0 - P + r, gw = w0 - P + cc;
            float v = 0.f;
            if (gh >= 0 && gh < H && gw >= 0 && gw < W)
                v = x[(((size_t)(b * C + cg + c)) << 14) + (gh << 7) + gw];
            sx[c][r][cc] = v;
        }
        __syncthreads();

#pragma unroll
        for (int c = 0; c < CG; ++c) {
            float center = sx[c][ty + P][tx + P];
#pragma unroll
            for (int di = 0; di < KSZ; ++di) {
#pragma unroll
                for (int dj = 0; dj < KSZ; ++dj) {
                    acc[di * KSZ + dj] += center * sx[c][ty + di][tx + dj];
                }
            }
        }
    }

    // cosine sim + softmax over the 49 window entries
    const float nc = sn[ty + P][tx + P];
    float m = -1e30f;
#pragma unroll
    for (int di = 0; di < KSZ; ++di) {
#pragma unroll
        for (int dj = 0; dj < KSZ; ++dj) {
            int k = di * KSZ + dj;
            float nn = sn[ty + di][tx + dj];
            float s = acc[k] / (nc * nn + EPS);
            acc[k] = s;
            m = fmaxf(m, s);
        }
    }
    float sum = 0.f;
#pragma unroll
    for (int k = 0; k < KK; ++k) {
        acc[k] = __expf(acc[k] - m);
        sum += acc[k];
    }
    const float inv = 1.f / sum;

    const size_t obase = ((size_t)b * KK) << 14;
    const int pix = ((h0 + ty) << 7) + (w0 + tx);
#pragma unroll
    for (int k = 0; k < KK; ++k)
        out[obase + ((size_t)k << 14) + pix] = acc[k] * inv;
}

extern "C" void kernel_launch(void* const* d_in, const int* in_sizes, int n_in,
                              void* d_out, int out_size, void* d_ws, size_t ws_size,
                              hipStream_t stream) {
    const float* x = (const float*)d_in[0];
    float* out = (float*)d_out;
    float* nrm = (float*)d_ws;   // NB*H*W floats = 256 KB

    // norms: one thread per pixel
    norms_kernel<<<(NB * H * W) / 256, 256, 0, stream>>>(x, nrm);

    dim3 block(TW, TH, 1);
    dim3 grid(W / TW, H / TH, NB);   // 2 x 32 x 4 = 256 blocks
    sim_kernel<<<grid, block, 0, stream>>>(x, nrm, out);
}

// Round 2
// 119.443 us; speedup vs baseline: 1.4998x; 1.4998x over previous
//
#include <hip/hip_runtime.h>
#include <math.h>

#define KK 49
#define H 128
#define W 128
#define C 64
#define NB 4
#define EPS 1e-7f

#define TLW 32            // tile width (pixels)
#define TLH 8             // tile height (pixels)
#define HW2 38            // halo width  = TLW + 6
#define HH2 14            // halo height = TLH + 6
#define NPOS (HW2 * HH2)  // 532 halo positions
#define PLANE (H * W)     // 16384

// Block: (64,4) = 256 threads. Lane layout: tx = w(0..31) + 32*s (s = channel half).
// Each thread: 2 vertically-adjacent pixels (rows 2*py, 2*py+1), 32 channels (its half),
// staged 4 channels/pass (8 passes), double-buffered LDS, shfl_xor(32) cross-half reduce.
__global__ __launch_bounds__(256, 1) void rsa_kernel(const float* __restrict__ x,
                                                     float* __restrict__ out) {
    __shared__ float4 sx4[2][2][HH2][HW2];  // [buf][half][r][col] -> 4 channels; 34 KB
    __shared__ float  sn2[2][NPOS];         // per-half partial sum of squares
    __shared__ float  snf[NPOS];            // final norms

    const int tx  = threadIdx.x;            // 0..63
    const int py  = threadIdx.y;            // 0..3 (pixel-pair row)
    const int w   = tx & 31;
    const int s   = tx >> 5;
    const int tid = py * 64 + tx;
    const int w0  = blockIdx.x * TLW;
    const int h0  = blockIdx.y * TLH;
    const int b   = blockIdx.z;
    const float* __restrict__ xb = x + (size_t)b * C * PLANE;

    // ---- staging slot metadata (identical every pass): i = tid + 256*j over [0, 2*NPOS)
    int  goff[5], lidx[5], chb[5];
    bool act[5], inb[5];
#pragma unroll
    for (int j = 0; j < 5; ++j) {
        int i = tid + j * 256;
        act[j] = (i < 2 * NPOS);
        int ii = act[j] ? i : 0;
        int half = (ii >= NPOS) ? 1 : 0;
        int pos  = ii - half * NPOS;
        int r    = pos / HW2;
        int col  = pos - r * HW2;
        int gh = h0 - 3 + r, gw = w0 - 3 + col;
        inb[j]  = (gh >= 0) && (gh < H) && (gw >= 0) && (gw < W);
        goff[j] = gh * W + gw;
        lidx[j] = ii;                 // flat float4 index within one buffer
        chb[j]  = half * 32;          // channel base for this slot's half
        if (act[j]) ((float*)sn2)[ii] = 0.f;
    }

    float4 pf[5];

    auto load_pass = [&](int t) {
#pragma unroll
        for (int j = 0; j < 5; ++j) {
            float4 v = make_float4(0.f, 0.f, 0.f, 0.f);
            if (act[j] && inb[j]) {
                const float* p = xb + (size_t)(chb[j] + t * 4) * PLANE + goff[j];
                v.x = p[0];
                v.y = p[PLANE];
                v.z = p[2 * PLANE];
                v.w = p[3 * PLANE];
            }
            pf[j] = v;
        }
    };

    auto write_pass = [&](int buf) {
#pragma unroll
        for (int j = 0; j < 5; ++j) {
            if (act[j]) {
                ((float4*)sx4[buf])[lidx[j]] = pf[j];
                float4 v = pf[j];
                ((float*)sn2)[lidx[j]] += v.x * v.x + v.y * v.y + v.z * v.z + v.w * v.w;
            }
        }
    };

    float acc0[KK], acc1[KK];
#pragma unroll
    for (int k = 0; k < KK; ++k) { acc0[k] = 0.f; acc1[k] = 0.f; }

    auto compute = [&](int buf) {
        const float4* base = &sx4[buf][s][0][0];
        const float4 c0 = base[(2 * py + 3) * HW2 + (w + 3)];
        const float4 c1 = base[(2 * py + 4) * HW2 + (w + 3)];
#pragma unroll
        for (int di = 0; di < 8; ++di) {
#pragma unroll
            for (int dj = 0; dj < 7; ++dj) {
                const float4 nv = base[(2 * py + di) * HW2 + (w + dj)];
                if (di < 7) {
                    int k = di * 7 + dj;
                    acc0[k] += c0.x * nv.x; acc0[k] += c0.y * nv.y;
                    acc0[k] += c0.z * nv.z; acc0[k] += c0.w * nv.w;
                }
                if (di > 0) {
                    int k = (di - 1) * 7 + dj;
                    acc1[k] += c1.x * nv.x; acc1[k] += c1.y * nv.y;
                    acc1[k] += c1.z * nv.z; acc1[k] += c1.w * nv.w;
                }
            }
        }
    };

    // ---- main loop: prefetch t+1 while computing t, double-buffered LDS
    load_pass(0);
    write_pass(0);
    __syncthreads();
#pragma unroll 2
    for (int t = 0; t < 8; ++t) {
        const int buf = t & 1;
        if (t < 7) load_pass(t + 1);
        compute(buf);
        if (t < 7) write_pass(buf ^ 1);
        __syncthreads();
    }

    // ---- norms: combine halves
    for (int i = tid; i < NPOS; i += 256) snf[i] = sqrtf(sn2[0][i] + sn2[1][i]);
    __syncthreads();

    // ---- cross-half reduce; lane s keeps pixel row 2*py+s
    const int pr = 2 * py + s;
    float vals[KK];
#pragma unroll
    for (int k = 0; k < KK; ++k) {
        float a0 = acc0[k] + __shfl_xor(acc0[k], 32, 64);
        float a1 = acc1[k] + __shfl_xor(acc1[k], 32, 64);
        vals[k] = s ? a1 : a0;
    }

    const float nc = snf[(pr + 3) * HW2 + (w + 3)];
    float m = -1e30f;
#pragma unroll
    for (int k = 0; k < KK; ++k) {
        const int di = k / 7, dj = k % 7;
        const float nn = snf[(pr + di) * HW2 + (w + dj)];
        const float sv = __fdividef(vals[k], nc * nn + EPS);
        vals[k] = sv;
        m = fmaxf(m, sv);
    }
    float sum = 0.f;
#pragma unroll
    for (int k = 0; k < KK; ++k) {
        vals[k] = __expf(vals[k] - m);
        sum += vals[k];
    }
    const float inv = __fdividef(1.f, sum);

    float* op = out + (((size_t)b * KK) << 14) + ((h0 + pr) << 7) + (w0 + w);
#pragma unroll
    for (int k = 0; k < KK; ++k) op[(size_t)k << 14] = vals[k] * inv;
}

extern "C" void kernel_launch(void* const* d_in, const int* in_sizes, int n_in,
                              void* d_out, int out_size, void* d_ws, size_t ws_size,
                              hipStream_t stream) {
    const float* x = (const float*)d_in[0];
    float* out = (float*)d_out;

    dim3 block(64, 4, 1);
    dim3 grid(W / TLW, H / TLH, NB);  // 4 x 16 x 4 = 256 blocks (1 per CU)
    rsa_kernel<<<grid, block, 0, stream>>>(x, out);
}